// Round 13
// baseline (121.890 us; speedup 1.0000x reference)
//
#include <hip/hip_runtime.h>
#include <hip/hip_bf16.h>
#include <hip/hip_fp16.h>

typedef __attribute__((ext_vector_type(8))) short short8;
typedef __attribute__((ext_vector_type(4))) short s16x4;
typedef __attribute__((ext_vector_type(4))) float f32x4;

#define BN 4
#define PN 1024
#define NN 16
#define C1N 64
#define C2N 64
#define KN 13
#define AN 12
#define KDIM 9984   // C1N*KN*AN, kk = k*768 + c*12 + a  (k=12 slice at 9216+)
#define NDIM 768    // C2N*AN
#define MDIM 4096   // BN*PN
#define NSPLIT 5    // uneven K split: 32,31,31,31,31 steps of BK=64 (total 156)
#define BK 64
#define BM 256      // GEMM block tile M
#define BNT 256     // GEMM block tile N

__device__ inline unsigned short f2bf(float x){
    unsigned int u = __float_as_uint(x);
    unsigned int r = (u + 0x7fffu + ((u >> 16) & 1u)) >> 16;
    return (unsigned short)r;
}
__device__ inline f32x4 bf4_to_f(s16x4 h){
    f32x4 r;
    r[0] = __uint_as_float(((unsigned)(unsigned short)h[0]) << 16);
    r[1] = __uint_as_float(((unsigned)(unsigned short)h[1]) << 16);
    r[2] = __uint_as_float(((unsigned)(unsigned short)h[2]) << 16);
    r[3] = __uint_as_float(((unsigned)(unsigned short)h[3]) << 16);
    return r;
}

// async global->LDS, 16B per lane. LDS dest = wave-uniform base + lane*16.
__device__ __forceinline__ void gload16(const unsigned short* g, unsigned short* l){
    __builtin_amdgcn_global_load_lds(
        (const __attribute__((address_space(1))) unsigned int*)(unsigned long long)(uintptr_t)g,
        (__attribute__((address_space(3))) unsigned int*)(unsigned int)(uintptr_t)l,
        16, 0, 0);
}

// ================= Kernel 1: interw | tr (both depend only on inputs) =================
// blocks [0,192): inter_w softmax; [192,3264): fm -> Am k=12 bf16 slice
__global__ __launch_bounds__(256) void k_p1(const int* __restrict__ nbr,
                                            const float* __restrict__ vert,
                                            const float* __restrict__ vs,
                                            const float* __restrict__ fm,
                                            float* __restrict__ iw,
                                            unsigned short* __restrict__ Am)
{
    int bid = blockIdx.x;
    if (bid < 192){
        // ---- interw: thread per (point, a) ----
        int t = bid * 256 + threadIdx.x;      // < 49152
        int pt = t / AN, a = t - pt * AN;
        int b = pt >> 10;
        float sx = vs[a*3+0], sy = vs[a*3+1], sz = vs[a*3+2];
        float sn = sqrtf(sx*sx + sy*sy + sz*sz);
        float si = 1.0f / fmaxf(sn, 1e-12f);
        sx *= si; sy *= si; sz *= si;
        float vx = vert[pt*3+0], vy = vert[pt*3+1], vz = vert[pt*3+2];
        float tt[NN];
        float mx = -1e30f;
        #pragma unroll
        for (int n = 0; n < NN; n++){
            int g = (b << 10) + nbr[pt*NN + n];
            float dx = vert[g*3+0] - vx;
            float dy = vert[g*3+1] - vy;
            float dz = vert[g*3+2] - vz;
            float nr = sqrtf(dx*dx + dy*dy + dz*dz);
            float inv = 1.0f / fmaxf(nr, 1e-12f);
            tt[n] = (dx*sx + dy*sy + dz*sz) * inv;
            mx = fmaxf(mx, tt[n]);
        }
        float s = 0.0f;
        #pragma unroll
        for (int n = 0; n < NN; n++){ tt[n] = expf(tt[n] - mx); s += tt[n]; }
        float inv = 1.0f / s;
        float* dst = iw + (size_t)t * NN;
        #pragma unroll
        for (int q = 0; q < 4; q++){
            float4 v = make_float4(tt[q*4]*inv, tt[q*4+1]*inv, tt[q*4+2]*inv, tt[q*4+3]*inv);
            *(float4*)(dst + q*4) = v;
        }
    } else {
        // ---- tr: fm -> bf16 own-feature slice Am[m][9216 + c*12 + a] ----
        int t = (bid - 192) * 256 + threadIdx.x;     // < 786432
        int a4 = t % 3;
        int rest = t / 3;                            // (b*64 + c)*1024 + p
        int p = rest & 1023;
        int bc = rest >> 10;
        int c = bc & 63, b = bc >> 6;
        float4 v = *(const float4*)(fm + (size_t)rest * 12 + a4*4);
        s16x4 h;
        h[0] = (short)f2bf(v.x); h[1] = (short)f2bf(v.y);
        h[2] = (short)f2bf(v.z); h[3] = (short)f2bf(v.w);
        int m = (b << 10) + p;
        *(s16x4*)(Am + (size_t)m * KDIM + 9216 + c*12 + a4*4) = h;
    }
}

// ================= Kernel 2: beff | newfeat (co-resident, hide each other's latency) =====
// blocks [0,2496): W_eff->Bm; [2496,4544): new_feat k=0..11 -> Am
__global__ __launch_bounds__(256) void k_p2(const float* __restrict__ W,
                                            const int* __restrict__ idx_map,
                                            const int* __restrict__ tiv,
                                            const int* __restrict__ tir,
                                            const int* __restrict__ nbr,
                                            const float* __restrict__ iw,
                                            unsigned short* __restrict__ Bm,
                                            unsigned short* Am)
{
    __shared__ int   nbs_s[2][NN];
    __shared__ float iwT_s[2][NN][AN];      // [point-in-block][n][k]
    int bid = blockIdx.x;
    if (bid < 2496){
        // ---- beff: thread per (d,r,k,c) ----
        int t = bid * 256 + threadIdx.x;   // < 638976
        int c = t & 63;
        int rest = t >> 6;          // < 9984
        int k = rest % KN;
        int rest2 = rest / KN;      // < 768
        int r = rest2 % AN;
        int d = rest2 / AN;
        int tv = tiv[r*KN + k];
        const float* wrow = W + (size_t)((d << 6) + c) * 36;
        s16x4 v0, v1, v2;
        #pragma unroll
        for (int a = 0; a < AN; a++){
            int s = idx_map[tv*AN + tir[r*AN + a]];
            unsigned short h = f2bf(wrow[s]);
            if (a < 4) v0[a] = (short)h;
            else if (a < 8) v1[a-4] = (short)h;
            else v2[a-8] = (short)h;
        }
        unsigned short* dst = Bm + ((size_t)(d*AN + r) * KDIM + k*768 + c*AN);
        s16x4* d4 = (s16x4*)dst;
        d4[0] = v0; d4[1] = v1; d4[2] = v2;
    } else {
        // ---- newfeat: 2 waves per point (k-halves), lane = channel c ----
        int t = threadIdx.x;
        int w = t >> 6, lane = t & 63;
        int pw = w >> 1, khalf = w & 1;
        int m = (bid - 2496) * 2 + pw;          // point id < 4096
        int b = m >> 10;

        if (khalf == 0){
            if (lane < NN) nbs_s[pw][lane] = nbr[m*NN + lane];
            #pragma unroll
            for (int i = 0; i < 3; i++){
                int idx = lane + i*64;              // < 192
                int a = idx >> 4, n = idx & 15;     // iw layout [a][n]
                iwT_s[pw][n][a] = iw[(size_t)m * (AN*NN) + idx];
            }
        }
        __syncthreads();

        f32x4 acc[6][3];
        #pragma unroll
        for (int k = 0; k < 6; k++)
            #pragma unroll
            for (int q = 0; q < 3; q++) acc[k][q] = (f32x4){0.f,0.f,0.f,0.f};

        int kb = khalf * 6;
        const unsigned short* slice = Am + 9216 + (size_t)lane * AN;

        #pragma unroll 2
        for (int n = 0; n < NN; n++){
            int mn = (b << 10) + nbs_s[pw][n];
            const unsigned short* src = slice + (size_t)mn * KDIM;
            s16x4 u0 = *(const s16x4*)(src);
            s16x4 u1 = *(const s16x4*)(src + 4);
            s16x4 u2 = *(const s16x4*)(src + 8);
            f32x4 v0 = bf4_to_f(u0), v1 = bf4_to_f(u1), v2 = bf4_to_f(u2);
            #pragma unroll
            for (int k = 0; k < 6; k++){
                float wv = iwT_s[pw][n][kb + k];
                acc[k][0] += v0 * wv;
                acc[k][1] += v1 * wv;
                acc[k][2] += v2 * wv;
            }
        }

        unsigned short* dst = Am + (size_t)m * KDIM + lane * AN;
        #pragma unroll
        for (int k = 0; k < 6; k++){
            s16x4 h0, h1, h2;
            #pragma unroll
            for (int j = 0; j < 4; j++){
                h0[j] = (short)f2bf(acc[k][0][j]);
                h1[j] = (short)f2bf(acc[k][1][j]);
                h2[j] = (short)f2bf(acc[k][2][j]);
            }
            s16x4* o = (s16x4*)(dst + (kb + k)*768);
            o[0] = h0; o[1] = h1; o[2] = h2;
        }
    }
}

// ---------------- Kernel 4: GEMM 256x256, 8 waves, dbuf BK=64, counted vmcnt (R10-exact) ----------------
// Per-wave tile 128x64 (2M x 4N). 1 block/CU, 8 waves = 2/SIMD. 128 KB LDS dbuf.
// Sync skeleton (proven race-free): barrier -> ISSUE(s+1) -> vmcnt(8) -> barrier -> BODY(s).
// 8 loads/thread/batch stay in flight across the whole body; never drains to 0 mid-loop.
// T2 swizzle: source chunk ch^(row&7), same XOR on read (involution; measured 0 conflicts).
// Split-K z=5, uneven: z0=32 steps, z1..4=31 (156 total); grid 16x3x5=240 = one CU round.
__global__ __launch_bounds__(512, 1) void k_gemm(const unsigned short* __restrict__ Am,
                                                 const unsigned short* __restrict__ Bm,
                                                 __half* __restrict__ part)
{
    __shared__ unsigned short Al[2][BM*BK];    // 2 x 32 KB
    __shared__ unsigned short Bl[2][BNT*BK];   // 2 x 32 KB
    int t = threadIdx.x;
    int lane = t & 63, w = t >> 6;
    int wr = w >> 2, wc = w & 3;               // 2M x 4N
    int l15 = lane & 15;
    int kofs = (lane >> 4) * 8;
    int m0 = blockIdx.x * BM, n0 = blockIdx.y * BNT;
    int z = blockIdx.z;
    int kstart = (z == 0) ? 0 : (32 + (z - 1) * 31);   // in BK units
    int nsteps = (z == 0) ? 32 : 31;
    int kbase = kstart * BK;

    // staging chunks: g = i*512 + t (i<4 for A, i<4 for B). row=g>>3, ch=g&7 (16B chunks).
    const unsigned short* gA[4];
    const unsigned short* gB[4];
    int lofsA[4], lofsB[4];
    #pragma unroll
    for (int i = 0; i < 4; i++){
        int g = i*512 + t;
        int row = g >> 3, ch = g & 7;
        int sch = ch ^ (row & 7);           // pre-swizzled source chunk (involution)
        gA[i] = Am + (size_t)(m0 + row) * KDIM + kbase + sch*8;
        gB[i] = Bm + (size_t)(n0 + row) * KDIM + kbase + sch*8;
        lofsA[i] = g * 8;
        lofsB[i] = g * 8;
    }

    f32x4 acc[8][4] = {};

#define ISSUE(S,KK) {                                                    \
        _Pragma("unroll")                                                \
        for (int i = 0; i < 4; i++) gload16(gA[i] + (KK), &Al[(S)&1][lofsA[i]]); \
        _Pragma("unroll")                                                \
        for (int i = 0; i < 4; i++) gload16(gB[i] + (KK), &Bl[(S)&1][lofsB[i]]); }

#define BODY(S) { const int cur_ = (S) & 1;                              \
        _Pragma("unroll")                                                \
        for (int kh = 0; kh < 2; kh++){                                  \
            int cc = kh*4 + (kofs >> 3);                                 \
            short8 af[8], bf[4];                                         \
            _Pragma("unroll")                                            \
            for (int i = 0; i < 8; i++){                                 \
                int ra = wr*128 + i*16 + l15;                            \
                af[i] = *(const short8*)&Al[cur_][ra*BK + ((cc ^ (ra & 7)) * 8)]; \
            }                                                            \
            _Pragma("unroll")                                            \
            for (int j = 0; j < 4; j++){                                 \
                int rb = wc*64 + j*16 + l15;                             \
                bf[j] = *(const short8*)&Bl[cur_][rb*BK + ((cc ^ (rb & 7)) * 8)]; \
            }                                                            \
            _Pragma("unroll")                                            \
            for (int i = 0; i < 8; i++){                                 \
                _Pragma("unroll")                                        \
                for (int j = 0; j < 4; j++)                              \
                    acc[i][j] = __builtin_amdgcn_mfma_f32_16x16x32_bf16(af[i], bf[j], acc[i][j], 0, 0, 0); \
            }                                                            \
        } }

    // prologue: stage tile 0 into buffer 0
    ISSUE(0, 0);

    for (int s = 0; s < nsteps; ++s){
        __builtin_amdgcn_s_barrier();            // WAR: all waves done reading buf[(s+1)&1]
        if (s + 1 < nsteps){
            ISSUE(s + 1, (s + 1) * BK);
            asm volatile("s_waitcnt vmcnt(8)" ::: "memory");
        } else {
            asm volatile("s_waitcnt vmcnt(0)" ::: "memory");
        }
        __builtin_amdgcn_s_barrier();            // RAW: every wave's batch-s loads landed
        BODY(s);
    }
#undef ISSUE
#undef BODY

    // epilogue: fp16 partials. C/D layout col=lane&15, row=(lane>>4)*4+q [m89-verified]
    __half* pp = part + (size_t)z * ((size_t)MDIM * NDIM);
    #pragma unroll
    for (int i = 0; i < 8; i++){
        #pragma unroll
        for (int j = 0; j < 4; j++){
            int col = n0 + wc*64 + j*16 + l15;
            #pragma unroll
            for (int q = 0; q < 4; q++){
                int row = m0 + wr*128 + i*16 + (lane >> 4)*4 + q;
                pp[(size_t)row * NDIM + col] = __float2half(acc[i][j][q]);
            }
        }
    }
}

// ---------------- Kernel 5: split-K reduce (fp16 partials) + scatter to bdpr ----------------
__global__ __launch_bounds__(256) void k_reduce(const __half* __restrict__ part,
                                                float* __restrict__ out)
{
    int t = blockIdx.x * 256 + threadIdx.x;        // per float4: MDIM*NDIM/4
    if (t >= MDIM * (NDIM/4)) return;
    int m = t / (NDIM/4);
    int n4 = (t - m * (NDIM/4)) * 4;
    f32x4 s = {};
    #pragma unroll
    for (int z = 0; z < NSPLIT; z++){
        const __half2* pz = (const __half2*)(part + (size_t)z * ((size_t)MDIM * NDIM) + (size_t)m * NDIM + n4);
        float2 a = __half22float2(pz[0]);
        float2 b = __half22float2(pz[1]);
        s[0] += a.x; s[1] += a.y; s[2] += b.x; s[3] += b.y;
    }
    int b = m >> 10, p = m & 1023;
    int d = n4 / AN, r = n4 - d*AN;    // r in {0,4,8}: never crosses d within 4
    *(f32x4*)(out + ((size_t)((b << 6) + d) * PN + p) * AN + r) = s;
}

extern "C" void kernel_launch(void* const* d_in, const int* in_sizes, int n_in,
                              void* d_out, int out_size, void* d_ws, size_t ws_size,
                              hipStream_t stream)
{
    const int*   nbr     = (const int*)  d_in[0];
    const float* vert    = (const float*)d_in[1];
    const float* fm      = (const float*)d_in[2];
    const float* W       = (const float*)d_in[3];
    const float* vs      = (const float*)d_in[4];
    const int*   idx_map = (const int*)  d_in[5];
    const int*   tiv     = (const int*)  d_in[6];
    const int*   tir     = (const int*)  d_in[7];
    float* out = (float*)d_out;

    char* ws = (char*)d_ws;
    float*          iw   = (float*)ws;                                  // 3,145,728 B
    unsigned short* Bm   = (unsigned short*)(ws + 3145728);             // 15,335,424 B
    unsigned short* Am   = (unsigned short*)(ws + 18481152);            // 81,788,928 B
    __half*         part = (__half*)(ws + 100270080);                   // 31,457,280 B (5 x fp16)

    k_p1    <<<3264, 256, 0, stream>>>(nbr, vert, vs, fm, iw, Am);
    k_p2    <<<4544, 256, 0, stream>>>(W, idx_map, tiv, tir, nbr, iw, Bm, Am);
    dim3 g(MDIM/BM, NDIM/BNT, NSPLIT);
    k_gemm  <<<g, 512, 0, stream>>>(Am, Bm, part);
    k_reduce<<<(MDIM*(NDIM/4))/256, 256, 0, stream>>>(part, out);
}

// Round 14
// 121.510 us; speedup vs baseline: 1.0031x; 1.0031x over previous
//
#include <hip/hip_runtime.h>
#include <hip/hip_bf16.h>
#include <hip/hip_fp16.h>

typedef __attribute__((ext_vector_type(8))) short short8;
typedef __attribute__((ext_vector_type(4))) short s16x4;
typedef __attribute__((ext_vector_type(4))) float f32x4;

#define BN 4
#define PN 1024
#define NN 16
#define C1N 64
#define C2N 64
#define KN 13
#define AN 12
#define KDIM 9984   // C1N*KN*AN, kk = k*768 + c*12 + a  (k=12 slice at 9216+)
#define NDIM 768    // C2N*AN
#define MDIM 4096   // BN*PN
#define NSPLIT 5    // even K split: 32,32,32,32,28 steps of BK=64 (total 156)
#define BK 64
#define BM 256
#define BNT 256

__device__ inline unsigned short f2bf(float x){
    unsigned int u = __float_as_uint(x);
    unsigned int r = (u + 0x7fffu + ((u >> 16) & 1u)) >> 16;
    return (unsigned short)r;
}
__device__ inline f32x4 bf4_to_f(s16x4 h){
    f32x4 r;
    r[0] = __uint_as_float(((unsigned)(unsigned short)h[0]) << 16);
    r[1] = __uint_as_float(((unsigned)(unsigned short)h[1]) << 16);
    r[2] = __uint_as_float(((unsigned)(unsigned short)h[2]) << 16);
    r[3] = __uint_as_float(((unsigned)(unsigned short)h[3]) << 16);
    return r;
}

// async global->LDS, 16B per lane. LDS dest = wave-uniform base + lane*16.
__device__ __forceinline__ void gload16(const unsigned short* g, unsigned short* l){
    __builtin_amdgcn_global_load_lds(
        (const __attribute__((address_space(1))) unsigned int*)(unsigned long long)(uintptr_t)g,
        (__attribute__((address_space(3))) unsigned int*)(unsigned int)(uintptr_t)l,
        16, 0, 0);
}

// ================= Kernel 1: fused prep (interw | beff | tr) — R10-proven =================
__global__ __launch_bounds__(256) void k_prep(const int* __restrict__ nbr,
                                              const float* __restrict__ vert,
                                              const float* __restrict__ vs,
                                              const float* __restrict__ W,
                                              const int* __restrict__ idx_map,
                                              const int* __restrict__ tiv,
                                              const int* __restrict__ tir,
                                              const float* __restrict__ fm,
                                              float* __restrict__ iw,
                                              unsigned short* __restrict__ Bm,
                                              unsigned short* __restrict__ Am)
{
    int bid = blockIdx.x;
    if (bid < 192){
        int t = bid * 256 + threadIdx.x;      // < 49152
        int pt = t / AN, a = t - pt * AN;
        int b = pt >> 10;
        float sx = vs[a*3+0], sy = vs[a*3+1], sz = vs[a*3+2];
        float sn = sqrtf(sx*sx + sy*sy + sz*sz);
        float si = 1.0f / fmaxf(sn, 1e-12f);
        sx *= si; sy *= si; sz *= si;
        float vx = vert[pt*3+0], vy = vert[pt*3+1], vz = vert[pt*3+2];
        float tt[NN];
        float mx = -1e30f;
        #pragma unroll
        for (int n = 0; n < NN; n++){
            int g = (b << 10) + nbr[pt*NN + n];
            float dx = vert[g*3+0] - vx;
            float dy = vert[g*3+1] - vy;
            float dz = vert[g*3+2] - vz;
            float nr = sqrtf(dx*dx + dy*dy + dz*dz);
            float inv = 1.0f / fmaxf(nr, 1e-12f);
            tt[n] = (dx*sx + dy*sy + dz*sz) * inv;
            mx = fmaxf(mx, tt[n]);
        }
        float s = 0.0f;
        #pragma unroll
        for (int n = 0; n < NN; n++){ tt[n] = expf(tt[n] - mx); s += tt[n]; }
        float inv = 1.0f / s;
        float* dst = iw + (size_t)t * NN;
        #pragma unroll
        for (int q = 0; q < 4; q++){
            float4 v = make_float4(tt[q*4]*inv, tt[q*4+1]*inv, tt[q*4+2]*inv, tt[q*4+3]*inv);
            *(float4*)(dst + q*4) = v;
        }
    } else if (bid < 2688){
        int t = (bid - 192) * 256 + threadIdx.x;   // < 638976
        int c = t & 63;
        int rest = t >> 6;
        int k = rest % KN;
        int rest2 = rest / KN;
        int r = rest2 % AN;
        int d = rest2 / AN;
        int tv = tiv[r*KN + k];
        const float* wrow = W + (size_t)((d << 6) + c) * 36;
        s16x4 v0, v1, v2;
        #pragma unroll
        for (int a = 0; a < AN; a++){
            int s = idx_map[tv*AN + tir[r*AN + a]];
            unsigned short h = f2bf(wrow[s]);
            if (a < 4) v0[a] = (short)h;
            else if (a < 8) v1[a-4] = (short)h;
            else v2[a-8] = (short)h;
        }
        unsigned short* dst = Bm + ((size_t)(d*AN + r) * KDIM + k*768 + c*AN);
        s16x4* d4 = (s16x4*)dst;
        d4[0] = v0; d4[1] = v1; d4[2] = v2;
    } else {
        int t = (bid - 2688) * 256 + threadIdx.x;     // < 786432
        int a4 = t % 3;
        int rest = t / 3;
        int p = rest & 1023;
        int bc = rest >> 10;
        int c = bc & 63, b = bc >> 6;
        float4 v = *(const float4*)(fm + (size_t)rest * 12 + a4*4);
        s16x4 h;
        h[0] = (short)f2bf(v.x); h[1] = (short)f2bf(v.y);
        h[2] = (short)f2bf(v.z); h[3] = (short)f2bf(v.w);
        int m = (b << 10) + p;
        *(s16x4*)(Am + (size_t)m * KDIM + 9216 + c*12 + a4*4) = h;
    }
}

// ---------------- Kernel 3: new_feat k=0..11 -> Am[m][k*768+c*12+a] — R10-proven ----------------
__global__ __launch_bounds__(256) void k_newfeat(const int* __restrict__ nbr,
                                                 const float* __restrict__ iw,
                                                 unsigned short* Am)
{
    __shared__ int   nbs_s[2][NN];
    __shared__ float iwT_s[2][NN][AN];
    int t = threadIdx.x;
    int w = t >> 6, lane = t & 63;
    int pw = w >> 1, khalf = w & 1;
    int m = blockIdx.x * 2 + pw;
    int b = m >> 10;

    if (khalf == 0){
        if (lane < NN) nbs_s[pw][lane] = nbr[m*NN + lane];
        #pragma unroll
        for (int i = 0; i < 3; i++){
            int idx = lane + i*64;
            int a = idx >> 4, n = idx & 15;
            iwT_s[pw][n][a] = iw[(size_t)m * (AN*NN) + idx];
        }
    }
    __syncthreads();

    f32x4 acc[6][3];
    #pragma unroll
    for (int k = 0; k < 6; k++)
        #pragma unroll
        for (int q = 0; q < 3; q++) acc[k][q] = (f32x4){0.f,0.f,0.f,0.f};

    int kb = khalf * 6;
    const unsigned short* slice = Am + 9216 + (size_t)lane * AN;

    #pragma unroll 2
    for (int n = 0; n < NN; n++){
        int mn = (b << 10) + nbs_s[pw][n];
        const unsigned short* src = slice + (size_t)mn * KDIM;
        s16x4 u0 = *(const s16x4*)(src);
        s16x4 u1 = *(const s16x4*)(src + 4);
        s16x4 u2 = *(const s16x4*)(src + 8);
        f32x4 v0 = bf4_to_f(u0), v1 = bf4_to_f(u1), v2 = bf4_to_f(u2);
        #pragma unroll
        for (int k = 0; k < 6; k++){
            float wv = iwT_s[pw][n][kb + k];
            acc[k][0] += v0 * wv;
            acc[k][1] += v1 * wv;
            acc[k][2] += v2 * wv;
        }
    }

    unsigned short* dst = Am + (size_t)m * KDIM + lane * AN;
    #pragma unroll
    for (int k = 0; k < 6; k++){
        s16x4 h0, h1, h2;
        #pragma unroll
        for (int j = 0; j < 4; j++){
            h0[j] = (short)f2bf(acc[k][0][j]);
            h1[j] = (short)f2bf(acc[k][1][j]);
            h2[j] = (short)f2bf(acc[k][2][j]);
        }
        s16x4* o = (s16x4*)(dst + (kb + k)*768);
        o[0] = h0; o[1] = h1; o[2] = h2;
    }
}

// ---------------- Kernel 4: GEMM 256x256, 8 waves, 4-phase/tile m201-style schedule ----------------
// LDS per buffer: A,B as kh-slabs [kh][256 rows][32 elems] (32 KB each); 2 buffers = 128 KB.
// Swizzle: 16B slot = chunk ^ ((row>>1)&3) (2-bit involution; applied on global source AND read).
// Phase = {ds_read 4 af (+4 bf on kh entry); stage ONE region of tile u+2; barrier;
//          lgkmcnt(0); setprio(1); 16 MFMA; setprio(0); barrier}.
// WAR: each phase stages only the region fully read in the PREVIOUS phase (barrier-separated).
// RAW: vmcnt(7) once per tile at P4 leaves exactly this tile's 7 stage-loads outstanding ->
// all of tile u+1 landed; never drains to 0 mid-loop. Region staging schedule:
//   P1: A(q1,kh1) of u+1   P2: A(q0,kh0)+B(kh0) of u+2   P3: A(q1,kh0) of u+2   P4: A(q0,kh1)+B(kh1) of u+2
__global__ __launch_bounds__(512, 1) void k_gemm(const unsigned short* __restrict__ Am,
                                                 const unsigned short* __restrict__ Bm,
                                                 __half* __restrict__ part)
{
    __shared__ unsigned short Al[2][2*256*32];   // [buf][kh*8192 + row*32 + slot*8]
    __shared__ unsigned short Bl[2][2*256*32];
    int t = threadIdx.x;
    int lane = t & 63, w = t >> 6;
    int wr = w >> 2, wc = w & 3;               // 2M x 4N
    int l15 = lane & 15;
    int lq  = lane >> 4;                       // k-chunk slot 0..3
    int m0 = blockIdx.x * BM, n0 = blockIdx.y * BNT;
    int z = blockIdx.z;
    int kbase = z * 32 * BK;
    int nsteps = (z == 4) ? 28 : 32;

    // per-thread staging decomposition
    // A-region(q,kh): 128 rows (64 per M-half) x 4 chunks = 512 slots, slot = t
    int rA  = (t >> 8) * 128 + ((t >> 2) & 63);   // row before +q*64 (within-run row)
    int chA = t & 3;
    int csA = chA ^ ((rA >> 1) & 3);              // pre-swizzled source chunk (q*64 keeps bits)
    // B-region(kh): 256 rows x 4 chunks = 1024 slots, slots i*512+t
    int rB0 = t >> 2,          chB0 = t & 3;
    int rB1 = (512 + t) >> 2,  chB1 = (512 + t) & 3;
    int csB0 = chB0 ^ ((rB0 >> 1) & 3);
    int csB1 = chB1 ^ ((rB1 >> 1) & 3);

    const unsigned short* gAq0 = Am + (size_t)(m0 + rA)      * KDIM + kbase + csA*8;
    const unsigned short* gAq1 = Am + (size_t)(m0 + 64 + rA) * KDIM + kbase + csA*8;
    const unsigned short* gBp0 = Bm + (size_t)(n0 + rB0) * KDIM + kbase + csB0*8;
    const unsigned short* gBp1 = Bm + (size_t)(n0 + rB1) * KDIM + kbase + csB1*8;
    int ldsAq0 = rA*32 + chA*8;
    int ldsAq1 = (64 + rA)*32 + chA*8;
    int ldsB0  = rB0*32 + chB0*8;
    int ldsB1  = rB1*32 + chB1*8;

    f32x4 acc[8][4] = {};

#define SA(U,Q,KH,BUF) gload16(((Q)? gAq1 : gAq0) + (U)*64 + (KH)*32, \
                               &Al[BUF][(KH)*8192 + ((Q)? ldsAq1 : ldsAq0)])
#define SB(U,KH,BUF) { gload16(gBp0 + (U)*64 + (KH)*32, &Bl[BUF][(KH)*8192 + ldsB0]); \
                       gload16(gBp1 + (U)*64 + (KH)*32, &Bl[BUF][(KH)*8192 + ldsB1]); }

#define RAF(i,Q,KH,CUR) ({ int ra_ = wr*128 + (Q)*64 + (i)*16 + l15; \
        *(const short8*)&Al[CUR][(KH)*8192 + ra_*32 + ((lq ^ ((ra_>>1)&3))*8)]; })
#define RBF(j,KH,CUR) ({ int rb_ = wc*64 + (j)*16 + l15; \
        *(const short8*)&Bl[CUR][(KH)*8192 + rb_*32 + ((lq ^ ((rb_>>1)&3))*8)]; })

#define MF(A,B,C) __builtin_amdgcn_mfma_f32_16x16x32_bf16(A,B,C,0,0,0)
#define MM16(QO) { \
    acc[QO+0][0]=MF(a0,bq0,acc[QO+0][0]); acc[QO+0][1]=MF(a0,bq1,acc[QO+0][1]); acc[QO+0][2]=MF(a0,bq2,acc[QO+0][2]); acc[QO+0][3]=MF(a0,bq3,acc[QO+0][3]); \
    acc[QO+1][0]=MF(a1,bq0,acc[QO+1][0]); acc[QO+1][1]=MF(a1,bq1,acc[QO+1][1]); acc[QO+1][2]=MF(a1,bq2,acc[QO+1][2]); acc[QO+1][3]=MF(a1,bq3,acc[QO+1][3]); \
    acc[QO+2][0]=MF(a2,bq0,acc[QO+2][0]); acc[QO+2][1]=MF(a2,bq1,acc[QO+2][1]); acc[QO+2][2]=MF(a2,bq2,acc[QO+2][2]); acc[QO+2][3]=MF(a2,bq3,acc[QO+2][3]); \
    acc[QO+3][0]=MF(a3,bq0,acc[QO+3][0]); acc[QO+3][1]=MF(a3,bq1,acc[QO+3][1]); acc[QO+3][2]=MF(a3,bq2,acc[QO+3][2]); acc[QO+3][3]=MF(a3,bq3,acc[QO+3][3]); }

#define BAR()  __builtin_amdgcn_s_barrier()
#define LGKM0() asm volatile("s_waitcnt lgkmcnt(0)" ::: "memory")

    // prologue: tile0 full (8 loads), tile1 minus A(q1,kh1) (7 loads)
    SA(0,0,0,0); SA(0,1,0,0); SA(0,0,1,0); SA(0,1,1,0); SB(0,0,0); SB(0,1,0);
    SA(1,0,0,1); SA(1,1,0,1); SA(1,0,1,1); SB(1,0,1); SB(1,1,1);
    asm volatile("s_waitcnt vmcnt(7)" ::: "memory");
    BAR();

    for (int u = 0; u < nsteps; ++u){
        const int cur = u & 1;
        const int nxt = cur ^ 1;
        const bool s1 = (u + 1 < nsteps);
        const bool s2 = (u + 2 < nsteps);
        short8 a0,a1,a2,a3, bq0,bq1,bq2,bq3;

        // P1: read (q0,kh0)+bf(kh0); stage A(q1,kh1) of u+1 -> nxt
        a0=RAF(0,0,0,cur); a1=RAF(1,0,0,cur); a2=RAF(2,0,0,cur); a3=RAF(3,0,0,cur);
        bq0=RBF(0,0,cur);  bq1=RBF(1,0,cur);  bq2=RBF(2,0,cur);  bq3=RBF(3,0,cur);
        if (s1) SA(u+1, 1, 1, nxt);
        BAR(); LGKM0();
        __builtin_amdgcn_s_setprio(1); MM16(0); __builtin_amdgcn_s_setprio(0);
        BAR();

        // P2: read (q1,kh0); stage A(q0,kh0)+B(kh0) of u+2 -> cur
        a0=RAF(0,1,0,cur); a1=RAF(1,1,0,cur); a2=RAF(2,1,0,cur); a3=RAF(3,1,0,cur);
        if (s2){ SA(u+2,0,0,cur); SB(u+2,0,cur); }
        BAR(); LGKM0();
        __builtin_amdgcn_s_setprio(1); MM16(4); __builtin_amdgcn_s_setprio(0);
        BAR();

        // P3: read (q0,kh1)+bf(kh1); stage A(q1,kh0) of u+2 -> cur
        a0=RAF(0,0,1,cur); a1=RAF(1,0,1,cur); a2=RAF(2,0,1,cur); a3=RAF(3,0,1,cur);
        bq0=RBF(0,1,cur);  bq1=RBF(1,1,cur);  bq2=RBF(2,1,cur);  bq3=RBF(3,1,cur);
        if (s2) SA(u+2,1,0,cur);
        BAR(); LGKM0();
        __builtin_amdgcn_s_setprio(1); MM16(0); __builtin_amdgcn_s_setprio(0);
        BAR();

        // P4: read (q1,kh1); stage A(q0,kh1)+B(kh1) of u+2 -> cur; counted vmcnt
        a0=RAF(0,1,1,cur); a1=RAF(1,1,1,cur); a2=RAF(2,1,1,cur); a3=RAF(3,1,1,cur);
        if (s2){ SA(u+2,0,1,cur); SB(u+2,1,cur); }
        BAR(); LGKM0();
        __builtin_amdgcn_s_setprio(1); MM16(4); __builtin_amdgcn_s_setprio(0);
        if (s2) { asm volatile("s_waitcnt vmcnt(7)" ::: "memory"); }
        else    { asm volatile("s_waitcnt vmcnt(0)" ::: "memory"); }
        BAR();
    }
#undef SA
#undef SB
#undef RAF
#undef RBF
#undef MF
#undef MM16
#undef BAR
#undef LGKM0

    // epilogue: fp16 partials. C/D layout col=lane&15, row=(lane>>4)*4+q [m89-verified]
    __half* pp = part + (size_t)z * ((size_t)MDIM * NDIM);
    #pragma unroll
    for (int i = 0; i < 8; i++){
        #pragma unroll
        for (int j = 0; j < 4; j++){
            int col = n0 + wc*64 + j*16 + l15;
            #pragma unroll
            for (int q = 0; q < 4; q++){
                int row = m0 + wr*128 + i*16 + (lane >> 4)*4 + q;
                pp[(size_t)row * NDIM + col] = __float2half(acc[i][j][q]);
            }
        }
    }
}

// ---------------- Kernel 5: split-K reduce (fp16 partials) + scatter to bdpr ----------------
__global__ __launch_bounds__(256) void k_reduce(const __half* __restrict__ part,
                                                float* __restrict__ out)
{
    int t = blockIdx.x * 256 + threadIdx.x;
    if (t >= MDIM * (NDIM/4)) return;
    int m = t / (NDIM/4);
    int n4 = (t - m * (NDIM/4)) * 4;
    f32x4 s = {};
    #pragma unroll
    for (int z = 0; z < NSPLIT; z++){
        const __half2* pz = (const __half2*)(part + (size_t)z * ((size_t)MDIM * NDIM) + (size_t)m * NDIM + n4);
        float2 a = __half22float2(pz[0]);
        float2 b = __half22float2(pz[1]);
        s[0] += a.x; s[1] += a.y; s[2] += b.x; s[3] += b.y;
    }
    int b = m >> 10, p = m & 1023;
    int d = n4 / AN, r = n4 - d*AN;
    *(f32x4*)(out + ((size_t)((b << 6) + d) * PN + p) * AN + r) = s;
}

extern "C" void kernel_launch(void* const* d_in, const int* in_sizes, int n_in,
                              void* d_out, int out_size, void* d_ws, size_t ws_size,
                              hipStream_t stream)
{
    const int*   nbr     = (const int*)  d_in[0];
    const float* vert    = (const float*)d_in[1];
    const float* fm      = (const float*)d_in[2];
    const float* W       = (const float*)d_in[3];
    const float* vs      = (const float*)d_in[4];
    const int*   idx_map = (const int*)  d_in[5];
    const int*   tiv     = (const int*)  d_in[6];
    const int*   tir     = (const int*)  d_in[7];
    float* out = (float*)d_out;

    char* ws = (char*)d_ws;
    float*          iw   = (float*)ws;                                  // 3,145,728 B
    unsigned short* Bm   = (unsigned short*)(ws + 3145728);             // 15,335,424 B
    unsigned short* Am   = (unsigned short*)(ws + 18481152);            // 81,788,928 B
    __half*         part = (__half*)(ws + 100270080);                   // 31,457,280 B (5 x fp16)

    k_prep   <<<5760, 256, 0, stream>>>(nbr, vert, vs, W, idx_map, tiv, tir, fm, iw, Bm, Am);
    k_newfeat<<<MDIM/2, 256, 0, stream>>>(nbr, iw, Am);
    dim3 g(MDIM/BM, NDIM/BNT, NSPLIT);
    k_gemm   <<<g, 512, 0, stream>>>(Am, Bm, part);
    k_reduce <<<(MDIM*(NDIM/4))/256, 256, 0, stream>>>(part, out);
}

// Round 15
// 115.546 us; speedup vs baseline: 1.0549x; 1.0516x over previous
//
#include <hip/hip_runtime.h>
#include <hip/hip_bf16.h>
#include <hip/hip_fp16.h>

typedef __attribute__((ext_vector_type(8))) short short8;
typedef __attribute__((ext_vector_type(4))) short s16x4;
typedef __attribute__((ext_vector_type(4))) float f32x4;

#define BN 4
#define PN 1024
#define NN 16
#define C1N 64
#define C2N 64
#define KN 13
#define AN 12
#define KDIM 9984   // C1N*KN*AN, kk = k*768 + c*12 + a  (k=12 slice at 9216+)
#define NDIM 768    // C2N*AN
#define MDIM 4096   // BN*PN
#define NSPLIT 5    // uneven K split: 32,31,31,31,31 steps of BK=64 (total 156)
#define BK 64
#define BM 256      // GEMM block tile M
#define BNT 256     // GEMM block tile N

__device__ inline unsigned short f2bf(float x){
    unsigned int u = __float_as_uint(x);
    unsigned int r = (u + 0x7fffu + ((u >> 16) & 1u)) >> 16;
    return (unsigned short)r;
}
__device__ inline f32x4 bf4_to_f(s16x4 h){
    f32x4 r;
    r[0] = __uint_as_float(((unsigned)(unsigned short)h[0]) << 16);
    r[1] = __uint_as_float(((unsigned)(unsigned short)h[1]) << 16);
    r[2] = __uint_as_float(((unsigned)(unsigned short)h[2]) << 16);
    r[3] = __uint_as_float(((unsigned)(unsigned short)h[3]) << 16);
    return r;
}

// async global->LDS, 16B per lane. LDS dest = wave-uniform base + lane*16.
__device__ __forceinline__ void gload16(const unsigned short* g, unsigned short* l){
    __builtin_amdgcn_global_load_lds(
        (const __attribute__((address_space(1))) unsigned int*)(unsigned long long)(uintptr_t)g,
        (__attribute__((address_space(3))) unsigned int*)(unsigned int)(uintptr_t)l,
        16, 0, 0);
}

// ================= Kernel 1: fused prep (interw | beff-LDS | tr) =================
// blocks [0,192): inter_w softmax
// blocks [192,960): beff, one block per (d,r): W[d] staged in LDS, coalesced writes
// blocks [960,1984): fm -> Am k=12 bf16 slice, one thread per (b,c,p)
__global__ __launch_bounds__(256) void k_prep(const int* __restrict__ nbr,
                                              const float* __restrict__ vert,
                                              const float* __restrict__ vs,
                                              const float* __restrict__ W,
                                              const int* __restrict__ idx_map,
                                              const int* __restrict__ tiv,
                                              const int* __restrict__ tir,
                                              const float* __restrict__ fm,
                                              float* __restrict__ iw,
                                              unsigned short* __restrict__ Bm,
                                              unsigned short* __restrict__ Am)
{
    __shared__ float Wl[64][37];     // +1 pad: bank (37c+s)%32 cycles all banks
    __shared__ int   s36s[KN][AN];
    int bid = blockIdx.x;
    int t = threadIdx.x;
    if (bid < 192){
        // ---- interw: thread per (point, a) ----
        int tt = bid * 256 + t;               // < 49152
        int pt = tt / AN, a = tt - pt * AN;
        int b = pt >> 10;
        float sx = vs[a*3+0], sy = vs[a*3+1], sz = vs[a*3+2];
        float sn = sqrtf(sx*sx + sy*sy + sz*sz);
        float si = 1.0f / fmaxf(sn, 1e-12f);
        sx *= si; sy *= si; sz *= si;
        float vx = vert[pt*3+0], vy = vert[pt*3+1], vz = vert[pt*3+2];
        float tv[NN];
        float mx = -1e30f;
        #pragma unroll
        for (int n = 0; n < NN; n++){
            int g = (b << 10) + nbr[pt*NN + n];
            float dx = vert[g*3+0] - vx;
            float dy = vert[g*3+1] - vy;
            float dz = vert[g*3+2] - vz;
            float nr = sqrtf(dx*dx + dy*dy + dz*dz);
            float inv = 1.0f / fmaxf(nr, 1e-12f);
            tv[n] = (dx*sx + dy*sy + dz*sz) * inv;
            mx = fmaxf(mx, tv[n]);
        }
        float s = 0.0f;
        #pragma unroll
        for (int n = 0; n < NN; n++){ tv[n] = expf(tv[n] - mx); s += tv[n]; }
        float inv = 1.0f / s;
        float* dst = iw + (size_t)tt * NN;
        #pragma unroll
        for (int q = 0; q < 4; q++){
            float4 v = make_float4(tv[q*4]*inv, tv[q*4+1]*inv, tv[q*4+2]*inv, tv[q*4+3]*inv);
            *(float4*)(dst + q*4) = v;
        }
    } else if (bid < 960){
        // ---- beff: one block per (d,r) = bid-192 ----
        int dr = bid - 192;
        int d = dr / AN, r = dr - d*AN;
        for (int i = t; i < C1N*36; i += 256){
            int c = i / 36, s = i - c*36;
            Wl[c][s] = W[(size_t)d * (C1N*36) + i];
        }
        if (t < KN*AN){
            int k = t / AN, a = t - (t/AN)*AN;
            s36s[k][a] = idx_map[ tiv[r*KN + k]*AN + tir[r*AN + a] ];
        }
        __syncthreads();
        int c = t & 63, kq = t >> 6;          // 4 k-groups per block
        unsigned short* brow = Bm + (size_t)dr * KDIM + c*AN;
        for (int k = kq; k < KN; k += 4){
            s16x4 v0, v1, v2;
            #pragma unroll
            for (int a = 0; a < AN; a++){
                unsigned short h = f2bf(Wl[c][s36s[k][a]]);
                if (a < 4) v0[a] = (short)h;
                else if (a < 8) v1[a-4] = (short)h;
                else v2[a-8] = (short)h;
            }
            s16x4* o = (s16x4*)(brow + k*768);
            o[0] = v0; o[1] = v1; o[2] = v2;
        }
    } else {
        // ---- tr: thread per (b,c,p): fm row -> Am[m][9216 + c*12 .. +12] ----
        int t2 = (bid - 960) * 256 + t;       // < 262144
        int p = t2 & 1023;
        int bc = t2 >> 10;
        int c = bc & 63, b = bc >> 6;
        const float* src = fm + (size_t)t2 * 12;
        float4 v0 = *(const float4*)(src);
        float4 v1 = *(const float4*)(src + 4);
        float4 v2 = *(const float4*)(src + 8);
        s16x4 h0, h1, h2;
        h0[0]=(short)f2bf(v0.x); h0[1]=(short)f2bf(v0.y); h0[2]=(short)f2bf(v0.z); h0[3]=(short)f2bf(v0.w);
        h1[0]=(short)f2bf(v1.x); h1[1]=(short)f2bf(v1.y); h1[2]=(short)f2bf(v1.z); h1[3]=(short)f2bf(v1.w);
        h2[0]=(short)f2bf(v2.x); h2[1]=(short)f2bf(v2.y); h2[2]=(short)f2bf(v2.z); h2[3]=(short)f2bf(v2.w);
        int m = (b << 10) + p;
        s16x4* o = (s16x4*)(Am + (size_t)m * KDIM + 9216 + c*12);
        o[0] = h0; o[1] = h1; o[2] = h2;
    }
}

// ---------------- Kernel 3: new_feat k=0..11 -> Am[m][k*768+c*12+a] — R10-proven ----------------
__global__ __launch_bounds__(256) void k_newfeat(const int* __restrict__ nbr,
                                                 const float* __restrict__ iw,
                                                 unsigned short* Am)
{
    __shared__ int   nbs_s[2][NN];
    __shared__ float iwT_s[2][NN][AN];
    int t = threadIdx.x;
    int w = t >> 6, lane = t & 63;
    int pw = w >> 1, khalf = w & 1;
    int m = blockIdx.x * 2 + pw;
    int b = m >> 10;

    if (khalf == 0){
        if (lane < NN) nbs_s[pw][lane] = nbr[m*NN + lane];
        #pragma unroll
        for (int i = 0; i < 3; i++){
            int idx = lane + i*64;
            int a = idx >> 4, n = idx & 15;
            iwT_s[pw][n][a] = iw[(size_t)m * (AN*NN) + idx];
        }
    }
    __syncthreads();

    f32x4 acc[6][3];
    #pragma unroll
    for (int k = 0; k < 6; k++)
        #pragma unroll
        for (int q = 0; q < 3; q++) acc[k][q] = (f32x4){0.f,0.f,0.f,0.f};

    int kb = khalf * 6;
    const unsigned short* slice = Am + 9216 + (size_t)lane * AN;

    #pragma unroll 2
    for (int n = 0; n < NN; n++){
        int mn = (b << 10) + nbs_s[pw][n];
        const unsigned short* src = slice + (size_t)mn * KDIM;
        s16x4 u0 = *(const s16x4*)(src);
        s16x4 u1 = *(const s16x4*)(src + 4);
        s16x4 u2 = *(const s16x4*)(src + 8);
        f32x4 v0 = bf4_to_f(u0), v1 = bf4_to_f(u1), v2 = bf4_to_f(u2);
        #pragma unroll
        for (int k = 0; k < 6; k++){
            float wv = iwT_s[pw][n][kb + k];
            acc[k][0] += v0 * wv;
            acc[k][1] += v1 * wv;
            acc[k][2] += v2 * wv;
        }
    }

    unsigned short* dst = Am + (size_t)m * KDIM + lane * AN;
    #pragma unroll
    for (int k = 0; k < 6; k++){
        s16x4 h0, h1, h2;
        #pragma unroll
        for (int j = 0; j < 4; j++){
            h0[j] = (short)f2bf(acc[k][0][j]);
            h1[j] = (short)f2bf(acc[k][1][j]);
            h2[j] = (short)f2bf(acc[k][2][j]);
        }
        s16x4* o = (s16x4*)(dst + (kb + k)*768);
        o[0] = h0; o[1] = h1; o[2] = h2;
    }
}

// ---------------- Kernel 4: GEMM 256x256, 8 waves, dbuf BK=64, counted vmcnt (R10-exact) ----------------
// Per-wave tile 128x64 (2M x 4N). 1 block/CU, 8 waves = 2/SIMD. 128 KB LDS dbuf.
// Sync skeleton (proven race-free): barrier -> ISSUE(s+1) -> vmcnt(8) -> barrier -> BODY(s).
// T2 swizzle: source chunk ch^(row&7), same XOR on read (involution; measured 0 conflicts).
// Split-K z=5, uneven: z0=32 steps, z1..4=31 (156 total); grid 16x3x5=240 = one CU round.
__global__ __launch_bounds__(512, 1) void k_gemm(const unsigned short* __restrict__ Am,
                                                 const unsigned short* __restrict__ Bm,
                                                 __half* __restrict__ part)
{
    __shared__ unsigned short Al[2][BM*BK];    // 2 x 32 KB
    __shared__ unsigned short Bl[2][BNT*BK];   // 2 x 32 KB
    int t = threadIdx.x;
    int lane = t & 63, w = t >> 6;
    int wr = w >> 2, wc = w & 3;               // 2M x 4N
    int l15 = lane & 15;
    int kofs = (lane >> 4) * 8;
    int m0 = blockIdx.x * BM, n0 = blockIdx.y * BNT;
    int z = blockIdx.z;
    int kstart = (z == 0) ? 0 : (32 + (z - 1) * 31);   // in BK units
    int nsteps = (z == 0) ? 32 : 31;
    int kbase = kstart * BK;

    const unsigned short* gA[4];
    const unsigned short* gB[4];
    int lofsA[4], lofsB[4];
    #pragma unroll
    for (int i = 0; i < 4; i++){
        int g = i*512 + t;
        int row = g >> 3, ch = g & 7;
        int sch = ch ^ (row & 7);           // pre-swizzled source chunk (involution)
        gA[i] = Am + (size_t)(m0 + row) * KDIM + kbase + sch*8;
        gB[i] = Bm + (size_t)(n0 + row) * KDIM + kbase + sch*8;
        lofsA[i] = g * 8;
        lofsB[i] = g * 8;
    }

    f32x4 acc[8][4] = {};

#define ISSUE(S,KK) {                                                    \
        _Pragma("unroll")                                                \
        for (int i = 0; i < 4; i++) gload16(gA[i] + (KK), &Al[(S)&1][lofsA[i]]); \
        _Pragma("unroll")                                                \
        for (int i = 0; i < 4; i++) gload16(gB[i] + (KK), &Bl[(S)&1][lofsB[i]]); }

#define BODY(S) { const int cur_ = (S) & 1;                              \
        _Pragma("unroll")                                                \
        for (int kh = 0; kh < 2; kh++){                                  \
            int cc = kh*4 + (kofs >> 3);                                 \
            short8 af[8], bf[4];                                         \
            _Pragma("unroll")                                            \
            for (int i = 0; i < 8; i++){                                 \
                int ra = wr*128 + i*16 + l15;                            \
                af[i] = *(const short8*)&Al[cur_][ra*BK + ((cc ^ (ra & 7)) * 8)]; \
            }                                                            \
            _Pragma("unroll")                                            \
            for (int j = 0; j < 4; j++){                                 \
                int rb = wc*64 + j*16 + l15;                             \
                bf[j] = *(const short8*)&Bl[cur_][rb*BK + ((cc ^ (rb & 7)) * 8)]; \
            }                                                            \
            _Pragma("unroll")                                            \
            for (int i = 0; i < 8; i++){                                 \
                _Pragma("unroll")                                        \
                for (int j = 0; j < 4; j++)                              \
                    acc[i][j] = __builtin_amdgcn_mfma_f32_16x16x32_bf16(af[i], bf[j], acc[i][j], 0, 0, 0); \
            }                                                            \
        } }

    // prologue: stage tile 0 into buffer 0
    ISSUE(0, 0);

    for (int s = 0; s < nsteps; ++s){
        __builtin_amdgcn_s_barrier();            // WAR: all waves done reading buf[(s+1)&1]
        if (s + 1 < nsteps){
            ISSUE(s + 1, (s + 1) * BK);
            asm volatile("s_waitcnt vmcnt(8)" ::: "memory");
        } else {
            asm volatile("s_waitcnt vmcnt(0)" ::: "memory");
        }
        __builtin_amdgcn_s_barrier();            // RAW: every wave's batch-s loads landed
        BODY(s);
    }
#undef ISSUE
#undef BODY

    // epilogue: fp16 partials. C/D layout col=lane&15, row=(lane>>4)*4+q [m89-verified]
    __half* pp = part + (size_t)z * ((size_t)MDIM * NDIM);
    #pragma unroll
    for (int i = 0; i < 8; i++){
        #pragma unroll
        for (int j = 0; j < 4; j++){
            int col = n0 + wc*64 + j*16 + l15;
            #pragma unroll
            for (int q = 0; q < 4; q++){
                int row = m0 + wr*128 + i*16 + (lane >> 4)*4 + q;
                pp[(size_t)row * NDIM + col] = __float2half(acc[i][j][q]);
            }
        }
    }
}

// ---------------- Kernel 5: split-K reduce (fp16 partials) + scatter to bdpr ----------------
__global__ __launch_bounds__(256) void k_reduce(const __half* __restrict__ part,
                                                float* __restrict__ out)
{
    int t = blockIdx.x * 256 + threadIdx.x;
    if (t >= MDIM * (NDIM/4)) return;
    int m = t / (NDIM/4);
    int n4 = (t - m * (NDIM/4)) * 4;
    f32x4 s = {};
    #pragma unroll
    for (int z = 0; z < NSPLIT; z++){
        const __half2* pz = (const __half2*)(part + (size_t)z * ((size_t)MDIM * NDIM) + (size_t)m * NDIM + n4);
        float2 a = __half22float2(pz[0]);
        float2 b = __half22float2(pz[1]);
        s[0] += a.x; s[1] += a.y; s[2] += b.x; s[3] += b.y;
    }
    int b = m >> 10, p = m & 1023;
    int d = n4 / AN, r = n4 - d*AN;
    *(f32x4*)(out + ((size_t)((b << 6) + d) * PN + p) * AN + r) = s;
}

extern "C" void kernel_launch(void* const* d_in, const int* in_sizes, int n_in,
                              void* d_out, int out_size, void* d_ws, size_t ws_size,
                              hipStream_t stream)
{
    const int*   nbr     = (const int*)  d_in[0];
    const float* vert    = (const float*)d_in[1];
    const float* fm      = (const float*)d_in[2];
    const float* W       = (const float*)d_in[3];
    const float* vs      = (const float*)d_in[4];
    const int*   idx_map = (const int*)  d_in[5];
    const int*   tiv     = (const int*)  d_in[6];
    const int*   tir     = (const int*)  d_in[7];
    float* out = (float*)d_out;

    char* ws = (char*)d_ws;
    float*          iw   = (float*)ws;                                  // 3,145,728 B
    unsigned short* Bm   = (unsigned short*)(ws + 3145728);             // 15,335,424 B
    unsigned short* Am   = (unsigned short*)(ws + 18481152);            // 81,788,928 B
    __half*         part = (__half*)(ws + 100270080);                   // 31,457,280 B (5 x fp16)

    k_prep   <<<1984, 256, 0, stream>>>(nbr, vert, vs, W, idx_map, tiv, tir, fm, iw, Bm, Am);
    k_newfeat<<<MDIM/2, 256, 0, stream>>>(nbr, iw, Am);
    dim3 g(MDIM/BM, NDIM/BNT, NSPLIT);
    k_gemm   <<<g, 512, 0, stream>>>(Am, Bm, part);
    k_reduce <<<(MDIM*(NDIM/4))/256, 256, 0, stream>>>(part, out);
}